// Round 14
// baseline (43.208 us; speedup 1.0000x reference)
//
#include <hip/hip_runtime.h>

#define TPB 256                        // 4 waves; half-row lanes -> 128 rows/chunk
#define CHUNK_ROWS 128
#define ROW_F 25
#define CHUNK_FA (CHUNK_ROWS * ROW_F)  // 3200 floats per array per chunk
#define CHUNK_F4A (CHUNK_FA / 4)       // 800 float4 per array per chunk
#define REM (CHUNK_F4A - 3 * TPB)      // 32 leftover f4 per array (t < 32)

// Slim judge for ONE group: ranks of out == ranks of pre (softmax monotone);
// "within" in scaled form |3*e_i - t_i*S| <= 0.09*S (no divide in the chain).
__device__ __forceinline__ void judge_group(const float* __restrict__ p,
                                            const float* __restrict__ t,
                                            int& calc, int& acc) {
    const float GAPv = 0.03f;   // 3 * 0.01
    float p0 = p[0], p1 = p[1], p2 = p[2], p3 = p[3];
    float t0 = t[0], t1 = t[1], t2 = t[2], t3 = t[3];

    float m  = fmaxf(fmaxf(p0, p1), fmaxf(p2, p3));
    float e0 = __expf(p0 - m), e1 = __expf(p1 - m);
    float e2 = __expf(p2 - m), e3 = __expf(p3 - m);
    float S  = (e0 + e1) + (e2 + e3);
    float thr = 0.09f * S;
    float w0 = fmaf(3.0f, e0, -t0 * S);
    float w1 = fmaf(3.0f, e1, -t1 * S);
    float w2 = fmaf(3.0f, e2, -t2 * S);
    float w3 = fmaf(3.0f, e3, -t3 * S);
    bool within = fabsf(w0) <= thr && fabsf(w1) <= thr &&
                  fabsf(w2) <= thr && fabsf(w3) <= thr;

    // stable ranks of p (== ranks of out). g_ij = (p_j < p_i), i<j.
    int g01 = p1 < p0, g02 = p2 < p0, g03 = p3 < p0;
    int g12 = p2 < p1, g13 = p3 < p1, g23 = p3 < p2;
    int ro0 = g01 + g02 + g03;
    int ro1 = 1 - g01 + g12 + g13;
    int ro2 = 2 - g02 - g12 + g23;
    int ro3 = 3 - g03 - g13 - g23;

    int h01 = t1 < t0, h02 = t2 < t0, h03 = t3 < t0;
    int h12 = t2 < t1, h13 = t3 < t1, h23 = t3 < t2;
    int rt0 = h01 + h02 + h03;
    int rt1 = 1 - h01 + h12 + h13;
    int rt2 = 2 - h02 - h12 + h23;
    int rt3 = 3 - h03 - h13 - h23;

    // sorted target values (ascending): st0 <= st1 <= st2
    float l01 = fminf(t0, t1), x01 = fmaxf(t0, t1);
    float l23 = fminf(t2, t3), x23 = fmaxf(t2, t3);
    float st0 = fminf(l01, l23), mlo = fmaxf(l01, l23);
    float mhi = fminf(x01, x23);
    float st1 = fminf(mlo, mhi), st2 = fmaxf(mlo, mhi);
    float d1 = st1 - st0;
    float d2 = st2 - st1;

    bool jump = within && (
        ((d1 < GAPv) & (d2 < GAPv)) ||
        ((d1 < GAPv) & (ro2 == rt2)) ||
        ((d2 < GAPv) & (ro0 == rt0)));

    int nz = (t0 == 0.0f) + (t1 == 0.0f) + (t2 == 0.0f) + (t3 == 0.0f);
    bool match_all = (ro0 == rt0) & (ro1 == rt1) & (ro2 == rt2) & (ro3 == rt3);

    bool s2 = ((ro0 == 2) & (rt0 == 2)) | ((ro1 == 2) & (rt1 == 2)) |
              ((ro2 == 2) & (rt2 == 2)) | ((ro3 == 2) & (rt3 == 2));
    bool s3 = ((ro0 == 3) & (rt0 == 3)) | ((ro1 == 3) & (rt1 == 3)) |
              ((ro2 == 3) & (rt2 == 3)) | ((ro3 == 3) & (rt3 == 3));

    bool c_lt2 = !jump & (nz < 2);
    bool c_eq2 = !jump & (nz == 2) & s2 & s3;
    bool c_eq3 = !jump & (nz == 3) & (ro3 == 3);

    calc += (jump | c_lt2 | c_eq2 | c_eq3) ? 1 : 0;
    acc  += (jump | (c_lt2 & match_all) | c_eq2 | c_eq3) ? 1 : 0;
}

__global__ __launch_bounds__(TPB, 3)
void recall_main_kernel(const float* __restrict__ pre,
                        const float* __restrict__ tar,
                        float* __restrict__ partial,
                        int B, int nchunks, int grid) {
    // double buffer: each buf = pre [0,3200) || tar [3200,6400) -> 2 x 25.6 KB
    __shared__ __align__(16) float s_buf[2][2 * CHUNK_FA];
    __shared__ float s_red[8];

    const int t    = threadIdx.x;
    const int lane = t & 63;
    const int wid  = t >> 6;
    const int total4 = (B * ROW_F) >> 2;   // per-array float4 count

    const float4* pre4 = (const float4*)pre;
    const float4* tar4 = (const float4*)tar;

    // half-row mapping: lanes l and l+32 share row (wid*32 + (l&31));
    // half h judges groups [3h, 3h+3) = floats [12h, 12h+12)
    const int row_local = (wid << 5) | (lane & 31);
    const int half = lane >> 5;
    const int off  = 12 * half;

    float csum = 0.0f, vsum = 0.0f;

    // two named staging register sets (depth-2 pipeline; never arrays)
    float4 a0, a1, a2, a3, b0, b1, b2, b3;   // set A
    float4 c0, c1, c2, c3, d0, d1, d2, d3;   // set B

#define LOAD_SET(P0,P1,P2,P3,T0,T1,T2,T3, cc)                                  \
    {                                                                          \
        const int base4 = (cc) * CHUNK_F4A;                                    \
        if (base4 + CHUNK_F4A <= total4) {                                     \
            P0 = pre4[base4 + t];                                              \
            P1 = pre4[base4 + TPB + t];                                        \
            P2 = pre4[base4 + 2 * TPB + t];                                    \
            T0 = tar4[base4 + t];                                              \
            T1 = tar4[base4 + TPB + t];                                        \
            T2 = tar4[base4 + 2 * TPB + t];                                    \
            if (t < REM) {                                                     \
                P3 = pre4[base4 + 3 * TPB + t];                                \
                T3 = tar4[base4 + 3 * TPB + t];                                \
            }                                                                  \
        } else {                                                               \
            int g0 = base4 + t,           g1 = base4 + TPB + t;                \
            int g2 = base4 + 2 * TPB + t, g3 = base4 + 3 * TPB + t;            \
            if (g0 >= total4) g0 = total4 - 1;                                 \
            if (g1 >= total4) g1 = total4 - 1;                                 \
            if (g2 >= total4) g2 = total4 - 1;                                 \
            if (g3 >= total4) g3 = total4 - 1;                                 \
            P0 = pre4[g0]; P1 = pre4[g1]; P2 = pre4[g2];                       \
            T0 = tar4[g0]; T1 = tar4[g1]; T2 = tar4[g2];                       \
            if (t < REM) { P3 = pre4[g3]; T3 = tar4[g3]; }                     \
        }                                                                      \
    }

#define WRITE_SET(P0,P1,P2,P3,T0,T1,T2,T3, buf)                                \
    {                                                                          \
        float4* sp = (float4*)(buf);                                           \
        float4* st = (float4*)((buf) + CHUNK_FA);                              \
        sp[t] = P0; sp[TPB + t] = P1; sp[2 * TPB + t] = P2;                    \
        st[t] = T0; st[TPB + t] = T1; st[2 * TPB + t] = T2;                    \
        if (t < REM) { sp[3 * TPB + t] = P3; st[3 * TPB + t] = T3; }           \
    }

#define COMPUTE(buf, cc)                                                       \
    {                                                                          \
        int row = (cc) * CHUNK_ROWS + row_local;                               \
        if (row < B) {                                                         \
            const float* rp = (buf) + row_local * ROW_F + off;                 \
            const float* rt = rp + CHUNK_FA;                                   \
            int calc = 0, acc = 0;                                             \
            judge_group(rp,     rt,     calc, acc);                            \
            judge_group(rp + 4, rt + 4, calc, acc);                            \
            judge_group(rp + 8, rt + 8, calc, acc);                            \
            int pack  = (acc << 8) | calc;                                     \
            int other = __shfl_xor(pack, 32);                                  \
            calc += other & 0xff;                                              \
            acc  += other >> 8;                                                \
            if (half == 0 && calc > 0) {                                       \
                csum += __fdividef((float)acc, (float)calc);                   \
                vsum += 1.0f;                                                  \
            }                                                                  \
        }                                                                      \
    }

    // ---- prologue: A <- chunk c (write now), B <- chunk c+g (held) ----
    int c = blockIdx.x;
    LOAD_SET(a0,a1,a2,a3,b0,b1,b2,b3, c);
    if (c + grid < nchunks)
        LOAD_SET(c0,c1,c2,c3,d0,d1,d2,d3, c + grid);
    WRITE_SET(a0,a1,a2,a3,b0,b1,b2,b3, s_buf[0]);
    __syncthreads();

    int cur = 0;
    while (true) {
        // phase 1: compute chunk c from buf[cur]; held set = B (c+g); free = A
        {
            int cn = c + 2 * grid;
            if (cn < nchunks) LOAD_SET(a0,a1,a2,a3,b0,b1,b2,b3, cn);
            COMPUTE(s_buf[cur], c);
            bool hasN = (c + grid) < nchunks;
            if (hasN) WRITE_SET(c0,c1,c2,c3,d0,d1,d2,d3, s_buf[cur ^ 1]);
            __syncthreads();
            c += grid; cur ^= 1;
            if (!hasN) break;
        }
        // phase 2: roles swapped; held set = A (c+g); free = B
        {
            int cn = c + 2 * grid;
            if (cn < nchunks) LOAD_SET(c0,c1,c2,c3,d0,d1,d2,d3, cn);
            COMPUTE(s_buf[cur], c);
            bool hasN = (c + grid) < nchunks;
            if (hasN) WRITE_SET(a0,a1,a2,a3,b0,b1,b2,b3, s_buf[cur ^ 1]);
            __syncthreads();
            c += grid; cur ^= 1;
            if (!hasN) break;
        }
    }

    // deterministic block reduction (4 waves)
#pragma unroll
    for (int offr = 32; offr > 0; offr >>= 1) {
        csum += __shfl_down(csum, offr);
        vsum += __shfl_down(vsum, offr);
    }
    if (lane == 0) { s_red[wid] = csum; s_red[4 + wid] = vsum; }
    __syncthreads();
    if (t == 0) {
        partial[2 * blockIdx.x]     = s_red[0] + s_red[1] + s_red[2] + s_red[3];
        partial[2 * blockIdx.x + 1] = s_red[4] + s_red[5] + s_red[6] + s_red[7];
    }
}

__global__ __launch_bounds__(256)
void recall_finalize_kernel(const float* __restrict__ partial, int n,
                            float* __restrict__ out) {
    __shared__ float s_red[8];
    float c = 0.0f, v = 0.0f;
    for (int i = threadIdx.x; i < n; i += 256) {
        c += partial[2 * i];
        v += partial[2 * i + 1];
    }
#pragma unroll
    for (int off = 32; off > 0; off >>= 1) {
        c += __shfl_down(c, off);
        v += __shfl_down(v, off);
    }
    int wave = threadIdx.x >> 6;
    if ((threadIdx.x & 63) == 0) { s_red[wave] = c; s_red[4 + wave] = v; }
    __syncthreads();
    if (threadIdx.x == 0) {
        float cs = s_red[0] + s_red[1] + s_red[2] + s_red[3];
        float vs = s_red[4] + s_red[5] + s_red[6] + s_red[7];
        out[0] = (vs > 0.0f) ? (cs / vs) : 0.0f;
    }
}

extern "C" void kernel_launch(void* const* d_in, const int* in_sizes, int n_in,
                              void* d_out, int out_size, void* d_ws, size_t ws_size,
                              hipStream_t stream) {
    const float* pre = (const float*)d_in[0];
    const float* tar = (const float*)d_in[1];
    float* out = (float*)d_out;
    float* partial = (float*)d_ws;                 // 768*2*4 = 6 KB

    int B = in_sizes[0] / ROW_F;
    int nchunks = (B + CHUNK_ROWS - 1) / CHUNK_ROWS;

    // 3 blocks/CU (51.2 KB LDS each) x 256 CU = 768 blocks
    int grid = 768;
    if (grid > nchunks) grid = nchunks;
    if (grid < 1) grid = 1;

    recall_main_kernel<<<grid, TPB, 0, stream>>>(pre, tar, partial, B, nchunks, grid);
    recall_finalize_kernel<<<1, 256, 0, stream>>>(partial, grid, out);
}

// Round 15
// 41.441 us; speedup vs baseline: 1.0426x; 1.0426x over previous
//
#include <hip/hip_runtime.h>

#define TPB 256                        // 4 waves; half-row lanes -> 128 rows/chunk
#define CHUNK_ROWS 128
#define ROW_F 25
#define CHUNK_FA (CHUNK_ROWS * ROW_F)  // 3200 floats per array per chunk
#define CHUNK_F4A (CHUNK_FA / 4)       // 800 float4 per array per chunk
#define REM (CHUNK_F4A - 3 * TPB)      // 32 leftover f4 per array (t < 32)

// Slim judge for ONE group: ranks of out == ranks of pre (softmax monotone);
// "within" in scaled form |3*e_i - t_i*S| <= 0.09*S (no divide in the chain).
__device__ __forceinline__ void judge_group(const float* __restrict__ p,
                                            const float* __restrict__ t,
                                            int& calc, int& acc) {
    const float GAPv = 0.03f;   // 3 * 0.01
    float p0 = p[0], p1 = p[1], p2 = p[2], p3 = p[3];
    float t0 = t[0], t1 = t[1], t2 = t[2], t3 = t[3];

    float m  = fmaxf(fmaxf(p0, p1), fmaxf(p2, p3));
    float e0 = __expf(p0 - m), e1 = __expf(p1 - m);
    float e2 = __expf(p2 - m), e3 = __expf(p3 - m);
    float S  = (e0 + e1) + (e2 + e3);
    float thr = 0.09f * S;
    float w0 = fmaf(3.0f, e0, -t0 * S);
    float w1 = fmaf(3.0f, e1, -t1 * S);
    float w2 = fmaf(3.0f, e2, -t2 * S);
    float w3 = fmaf(3.0f, e3, -t3 * S);
    bool within = fabsf(w0) <= thr && fabsf(w1) <= thr &&
                  fabsf(w2) <= thr && fabsf(w3) <= thr;

    // stable ranks of p (== ranks of out). g_ij = (p_j < p_i), i<j.
    int g01 = p1 < p0, g02 = p2 < p0, g03 = p3 < p0;
    int g12 = p2 < p1, g13 = p3 < p1, g23 = p3 < p2;
    int ro0 = g01 + g02 + g03;
    int ro1 = 1 - g01 + g12 + g13;
    int ro2 = 2 - g02 - g12 + g23;
    int ro3 = 3 - g03 - g13 - g23;

    int h01 = t1 < t0, h02 = t2 < t0, h03 = t3 < t0;
    int h12 = t2 < t1, h13 = t3 < t1, h23 = t3 < t2;
    int rt0 = h01 + h02 + h03;
    int rt1 = 1 - h01 + h12 + h13;
    int rt2 = 2 - h02 - h12 + h23;
    int rt3 = 3 - h03 - h13 - h23;

    // sorted target values (ascending): st0 <= st1 <= st2
    float l01 = fminf(t0, t1), x01 = fmaxf(t0, t1);
    float l23 = fminf(t2, t3), x23 = fmaxf(t2, t3);
    float st0 = fminf(l01, l23), mlo = fmaxf(l01, l23);
    float mhi = fminf(x01, x23);
    float st1 = fminf(mlo, mhi), st2 = fmaxf(mlo, mhi);
    float d1 = st1 - st0;
    float d2 = st2 - st1;

    bool jump = within && (
        ((d1 < GAPv) & (d2 < GAPv)) ||
        ((d1 < GAPv) & (ro2 == rt2)) ||
        ((d2 < GAPv) & (ro0 == rt0)));

    int nz = (t0 == 0.0f) + (t1 == 0.0f) + (t2 == 0.0f) + (t3 == 0.0f);
    bool match_all = (ro0 == rt0) & (ro1 == rt1) & (ro2 == rt2) & (ro3 == rt3);

    bool s2 = ((ro0 == 2) & (rt0 == 2)) | ((ro1 == 2) & (rt1 == 2)) |
              ((ro2 == 2) & (rt2 == 2)) | ((ro3 == 2) & (rt3 == 2));
    bool s3 = ((ro0 == 3) & (rt0 == 3)) | ((ro1 == 3) & (rt1 == 3)) |
              ((ro2 == 3) & (rt2 == 3)) | ((ro3 == 3) & (rt3 == 3));

    bool c_lt2 = !jump & (nz < 2);
    bool c_eq2 = !jump & (nz == 2) & s2 & s3;
    bool c_eq3 = !jump & (nz == 3) & (ro3 == 3);

    calc += (jump | c_lt2 | c_eq2 | c_eq3) ? 1 : 0;
    acc  += (jump | (c_lt2 & match_all) | c_eq2 | c_eq3) ? 1 : 0;
}

__global__ __launch_bounds__(TPB, 3)
void recall_main_kernel(const float* __restrict__ pre,
                        const float* __restrict__ tar,
                        float* __restrict__ partial,
                        int B, int nchunks, int grid) {
    // double buffer: each buf = pre [0,3200) || tar [3200,6400) -> 2 x 25.6 KB
    __shared__ __align__(16) float s_buf[2][2 * CHUNK_FA];
    __shared__ float s_red[8];

    const int t    = threadIdx.x;
    const int lane = t & 63;
    const int wid  = t >> 6;
    const int total4 = (B * ROW_F) >> 2;   // per-array float4 count

    const float4* pre4 = (const float4*)pre;
    const float4* tar4 = (const float4*)tar;

    // half-row mapping: lanes l and l+32 share row (wid*32 + (l&31));
    // half h judges groups [3h, 3h+3) = floats [12h, 12h+12)
    const int row_local = (wid << 5) | (lane & 31);
    const int half = lane >> 5;
    const int off  = 12 * half;

    float csum = 0.0f, vsum = 0.0f;

    // named staging registers (never arrays -> never scratch)
    float4 a0, a1, a2, a3, b0, b1, b2, b3;

    // ---- load chunk c's 25.6 KB into registers (issue only; no wait) ----
    auto load_chunk = [&](int c) {
        const int base4 = c * CHUNK_F4A;
        if (base4 + CHUNK_F4A <= total4) {
            a0 = pre4[base4 + t];
            a1 = pre4[base4 + TPB + t];
            a2 = pre4[base4 + 2 * TPB + t];
            b0 = tar4[base4 + t];
            b1 = tar4[base4 + TPB + t];
            b2 = tar4[base4 + 2 * TPB + t];
            if (t < REM) {
                a3 = pre4[base4 + 3 * TPB + t];
                b3 = tar4[base4 + 3 * TPB + t];
            }
        } else {
            int g0 = base4 + t,          g1 = base4 + TPB + t;
            int g2 = base4 + 2 * TPB + t, g3 = base4 + 3 * TPB + t;
            if (g0 >= total4) g0 = total4 - 1;
            if (g1 >= total4) g1 = total4 - 1;
            if (g2 >= total4) g2 = total4 - 1;
            if (g3 >= total4) g3 = total4 - 1;
            a0 = pre4[g0]; a1 = pre4[g1]; a2 = pre4[g2];
            b0 = tar4[g0]; b1 = tar4[g1]; b2 = tar4[g2];
            if (t < REM) { a3 = pre4[g3]; b3 = tar4[g3]; }
        }
    };
    // ---- write staged registers into LDS buffer ----
    auto write_chunk = [&](float* buf) {
        float4* sp = (float4*)buf;                 // pre half
        float4* st = (float4*)(buf + CHUNK_FA);    // tar half
        sp[t] = a0; sp[TPB + t] = a1; sp[2 * TPB + t] = a2;
        st[t] = b0; st[TPB + t] = b1; st[2 * TPB + t] = b2;
        if (t < REM) { sp[3 * TPB + t] = a3; st[3 * TPB + t] = b3; }
    };

    // prologue: stage first chunk
    int c = blockIdx.x;
    load_chunk(c);
    write_chunk(s_buf[0]);
    __syncthreads();

    int cur = 0;
    for (; c < nchunks; c += grid) {
        const int nc = c + grid;
        const bool has_next = nc < nchunks;

        if (has_next) load_chunk(nc);        // loads fly during compute below

        int row = c * CHUNK_ROWS + row_local;
        if (row < B) {
            const float* rp = &s_buf[cur][row_local * ROW_F + off];
            const float* rt = rp + CHUNK_FA;
            int calc = 0, acc = 0;
            judge_group(rp,     rt,     calc, acc);
            judge_group(rp + 4, rt + 4, calc, acc);
            judge_group(rp + 8, rt + 8, calc, acc);
            // merge lane pair (l, l+32): one packed shuffle
            int pack  = (acc << 8) | calc;
            int other = __shfl_xor(pack, 32);
            calc += other & 0xff;
            acc  += other >> 8;
            if (half == 0 && calc > 0) {
                csum += __fdividef((float)acc, (float)calc);
                vsum += 1.0f;
            }
        }

        if (has_next) write_chunk(s_buf[cur ^ 1]);  // vmcnt waits land here
        __syncthreads();                             // one barrier per iteration
        cur ^= 1;
    }

    // deterministic block reduction (4 waves)
#pragma unroll
    for (int offr = 32; offr > 0; offr >>= 1) {
        csum += __shfl_down(csum, offr);
        vsum += __shfl_down(vsum, offr);
    }
    if (lane == 0) { s_red[wid] = csum; s_red[4 + wid] = vsum; }
    __syncthreads();
    if (t == 0) {
        partial[2 * blockIdx.x]     = s_red[0] + s_red[1] + s_red[2] + s_red[3];
        partial[2 * blockIdx.x + 1] = s_red[4] + s_red[5] + s_red[6] + s_red[7];
    }
}

__global__ __launch_bounds__(256)
void recall_finalize_kernel(const float* __restrict__ partial, int n,
                            float* __restrict__ out) {
    __shared__ float s_red[8];
    float c = 0.0f, v = 0.0f;
    for (int i = threadIdx.x; i < n; i += 256) {
        c += partial[2 * i];
        v += partial[2 * i + 1];
    }
#pragma unroll
    for (int off = 32; off > 0; off >>= 1) {
        c += __shfl_down(c, off);
        v += __shfl_down(v, off);
    }
    int wave = threadIdx.x >> 6;
    if ((threadIdx.x & 63) == 0) { s_red[wave] = c; s_red[4 + wave] = v; }
    __syncthreads();
    if (threadIdx.x == 0) {
        float cs = s_red[0] + s_red[1] + s_red[2] + s_red[3];
        float vs = s_red[4] + s_red[5] + s_red[6] + s_red[7];
        out[0] = (vs > 0.0f) ? (cs / vs) : 0.0f;
    }
}

extern "C" void kernel_launch(void* const* d_in, const int* in_sizes, int n_in,
                              void* d_out, int out_size, void* d_ws, size_t ws_size,
                              hipStream_t stream) {
    const float* pre = (const float*)d_in[0];
    const float* tar = (const float*)d_in[1];
    float* out = (float*)d_out;
    float* partial = (float*)d_ws;                 // 768*2*4 = 6 KB

    int B = in_sizes[0] / ROW_F;
    int nchunks = (B + CHUNK_ROWS - 1) / CHUNK_ROWS;

    // 3 blocks/CU (51.2 KB LDS each) x 256 CU = 768 blocks
    int grid = 768;
    if (grid > nchunks) grid = nchunks;
    if (grid < 1) grid = 1;

    recall_main_kernel<<<grid, TPB, 0, stream>>>(pre, tar, partial, B, nchunks, grid);
    recall_finalize_kernel<<<1, 256, 0, stream>>>(partial, grid, out);
}